// Round 9
// baseline (598.534 us; speedup 1.0000x reference)
//
#include <hip/hip_runtime.h>
#include <hip/hip_bf16.h>
#include <stdint.h>

#define DIM   3072
#define BATCH 16384

typedef __attribute__((ext_vector_type(8))) short bf16x8;
typedef __attribute__((ext_vector_type(4))) float f32x4;

__device__ __forceinline__ unsigned short f2b(float f) {
    union { float f; unsigned u; } c; c.f = f;
    unsigned u = c.u;
    unsigned r = (u + 0x7fffu + ((u >> 16) & 1u)) >> 16;
    return (unsigned short)r;
}

// ======== merged pre-pass (R6-proven) ========
#define NWT   2304
#define NCVT  2048
__global__ __launch_bounds__(256) void prep_kernel(const float* __restrict__ w,
                                                   const float* __restrict__ mask,
                                                   const float* __restrict__ x,
                                                   ushort* __restrict__ wt,
                                                   ushort* __restrict__ xb) {
    if (blockIdx.x < NWT) {
        __shared__ float tile[64][65];
        const int u0 = (blockIdx.x % 48) * 64;
        const int d0 = (blockIdx.x / 48) * 64;
        const int t  = threadIdx.x;
        const int rr = t >> 4, cc = t & 15;
#pragma unroll
        for (int it = 0; it < 4; ++it) {
            int drow = it * 16 + rr;
            float4 v = *reinterpret_cast<const float4*>(&w[(size_t)(d0 + drow) * DIM + u0 + cc * 4]);
            tile[drow][cc * 4 + 0] = v.x;
            tile[drow][cc * 4 + 1] = v.y;
            tile[drow][cc * 4 + 2] = v.z;
            tile[drow][cc * 4 + 3] = v.w;
        }
        __syncthreads();
#pragma unroll
        for (int it = 0; it < 4; ++it) {
            int urow = it * 16 + rr;
            float4 mv = *reinterpret_cast<const float4*>(&mask[(size_t)(u0 + urow) * DIM + d0 + cc * 4]);
            ushort4 o;
            o.x = f2b(tile[cc * 4 + 0][urow] * mv.x);
            o.y = f2b(tile[cc * 4 + 1][urow] * mv.y);
            o.z = f2b(tile[cc * 4 + 2][urow] * mv.z);
            o.w = f2b(tile[cc * 4 + 3][urow] * mv.w);
            *reinterpret_cast<ushort4*>(&wt[(size_t)(u0 + urow) * DIM + d0 + cc * 4]) = o;
        }
    } else {
        const int n4 = BATCH * DIM / 4;
        const int stride = NCVT * 256;
        for (int i = (blockIdx.x - NWT) * 256 + threadIdx.x; i < n4; i += stride) {
            float4 v = reinterpret_cast<const float4*>(x)[i];
            ushort4 o;
            o.x = f2b(v.x); o.y = f2b(v.y); o.z = f2b(v.z); o.w = f2b(v.w);
            reinterpret_cast<ushort4*>(xb)[i] = o;
        }
    }
}

#define GLOAD_LDS16(g, l)                                                                 \
    __builtin_amdgcn_global_load_lds((const __attribute__((address_space(1))) void*)(g),  \
                                     (__attribute__((address_space(3))) void*)(l), 16, 0, 0)

// ============ persistent 256² 8-phase bf16 GEMM + 1-phase ds_read read-ahead ============
// Identical staging/vmcnt/barrier skeleton to R8. ds_reads for phase p+1 are issued in
// phase p AFTER the barrier+lgkmcnt(0) (staged-data visibility already established by the
// preceding vmcnt+barrier), so they complete under phase p's MFMA cluster.
// A-frags ping-pong (a0_/a1_); b-frag lifetimes already alternate.
__global__ __launch_bounds__(512, 1) void gemm8p(const ushort* __restrict__ A,
                                                 const ushort* __restrict__ B,
                                                 const float* __restrict__ bias,
                                                 float* __restrict__ C) {
    __shared__ ushort sh[2 * 2 * 16384];   // [buf][side A=0/B=1][256][64] : 128 KB

    const int tid  = threadIdx.x;
    const int lane = tid & 63;
    const int wid  = tid >> 6;   // 0..7
    const int wr   = wid >> 2;   // 0..1  (M)
    const int wc   = wid & 3;    // 0..3  (N)
    const int l15  = lane & 15;
    const int kg   = lane >> 4;
    const int sx   = lane & 7;

    const int srow = lane >> 3;
    const int sg   = (lane & 7) ^ srow;

    const int bx  = blockIdx.x;
    const int xcd = bx & 7, loc = bx >> 3;
    int q    = xcd * 96 + loc;
    int brow = (q / 12) * 256, bcol = (q % 12) * 256;
    int nrow = brow, ncol = bcol, nvalid = 0;

    f32x4 acc[8][4] = {};
    bf16x8 a0_[8], a1_[8], b0_[4], b1_[4];
    const f32x4 fzero = {};

#define STAGE(b, side, h, tt)                                                              \
    do {                                                                                   \
        int _tt = (tt);                                                                    \
        int _t  = (_tt < 48) ? _tt : (nvalid ? _tt - 48 : 47);                             \
        int _rb = (_tt < 48) ? ((side) ? bcol : brow) : ((side) ? ncol : nrow);            \
        const ushort* _base = (side) ? B : A;                                              \
        int _r0 = _rb + (h) * 128 + wid * 16 + srow;                                       \
        const ushort* _g0 = _base + (size_t)_r0 * DIM + _t * 64 + sg * 8;                  \
        ushort* _l0 = sh + ((b) * 2 + (side)) * 16384 + (h) * 8192 + wid * 1024;           \
        GLOAD_LDS16(_g0, _l0);                                                             \
        GLOAD_LDS16(_g0 + (size_t)8 * DIM, _l0 + 512);                                     \
    } while (0)

#define LDA(DST, QB, QM)                                                                   \
    _Pragma("unroll") for (int fm = 0; fm < 4; ++fm)                                       \
    _Pragma("unroll") for (int ks = 0; ks < 2; ++ks)                                       \
        DST[fm * 2 + ks] = *reinterpret_cast<const bf16x8*>(                               \
            sh + (QB) * 32768 + (wr * 128 + (QM) * 64 + fm * 16 + l15) * 64 +              \
            (((ks * 4 + kg) ^ sx) * 8));

#define LDB(DST, QB, QN)                                                                   \
    _Pragma("unroll") for (int fn = 0; fn < 2; ++fn)                                       \
    _Pragma("unroll") for (int ks = 0; ks < 2; ++ks)                                       \
        DST[fn * 2 + ks] = *reinterpret_cast<const bf16x8*>(                               \
            sh + (QB) * 32768 + 16384 + (wc * 64 + (QN) * 32 + fn * 16 + l15) * 64 +       \
            (((ks * 4 + kg) ^ sx) * 8));

#define MMQ(AARR, BARR, QM, QN)                                                            \
    _Pragma("unroll") for (int fm = 0; fm < 4; ++fm)                                       \
    _Pragma("unroll") for (int fn = 0; fn < 2; ++fn)                                       \
    _Pragma("unroll") for (int ks = 0; ks < 2; ++ks)                                       \
        acc[(QM) * 4 + fm][(QN) * 2 + fn] = __builtin_amdgcn_mfma_f32_16x16x32_bf16(       \
            AARR[fm * 2 + ks], BARR[fn * 2 + ks], acc[(QM) * 4 + fm][(QN) * 2 + fn], 0, 0, 0);

    // barrier + drain prior-phase ds_reads; sched_barrier pins everything below
#define MID0()                                                                             \
    __builtin_amdgcn_s_barrier();                                                          \
    asm volatile("s_waitcnt lgkmcnt(0)" ::: "memory");                                     \
    __builtin_amdgcn_sched_barrier(0);

    // pin read-issue above, run MFMA cluster under setprio(1), close phase
#define DOMM(AARR, BARR, QM, QN)                                                           \
    __builtin_amdgcn_sched_barrier(0);                                                     \
    __builtin_amdgcn_s_setprio(1);                                                         \
    MMQ(AARR, BARR, QM, QN);                                                               \
    __builtin_amdgcn_s_setprio(0);                                                         \
    __builtin_amdgcn_s_barrier();

#define VMW4() asm volatile("s_waitcnt vmcnt(4)" ::: "memory");

    // ---- prologue (tile 0): t0 fully -> buf0, B(t1) -> buf1; leave t1.B in flight ----
    STAGE(0, 0, 0, 0);
    STAGE(0, 0, 1, 0);
    STAGE(0, 1, 0, 0);
    STAGE(0, 1, 1, 0);
    STAGE(1, 1, 0, 1);
    STAGE(1, 1, 1, 1);
    VMW4();
    __builtin_amdgcn_s_barrier();
    // read-ahead for P1 (buf0 valid after the vmcnt+barrier above)
    LDA(a0_, 0, 0);
    LDB(b0_, 0, 0);

    for (int r = 0; r < 3; ++r) {
        nvalid = (r < 2);
        int qn = nvalid ? (xcd * 96 + (r + 1) * 32 + loc) : q;
        nrow = (qn / 12) * 256;
        ncol = (qn % 12) * 256;

        float bv[4];
#pragma unroll
        for (int n = 0; n < 4; ++n) bv[n] = bias[bcol + wc * 64 + n * 16 + l15];

        for (int t = 0; t < 48; t += 2) {
            // P1: MFMA t.Q(0,0) [a0_,b0_]      issue b1_(t)        stage A0(t+1)->buf1
            STAGE(1, 0, 0, t + 1);
            MID0();
            LDB(b1_, 0, 1);
            DOMM(a0_, b0_, 0, 0);
            // P2: Q(0,1) [a0_,b1_]             issue a1_ = LDA(0,1) stage A1(t+1)->buf1
            STAGE(1, 0, 1, t + 1);
            MID0();
            LDA(a1_, 0, 1);
            DOMM(a0_, b1_, 0, 1);
            // P3: Q(1,0) [a1_,b0_]             (no reads)           stage B0(t+2)->buf0
            STAGE(0, 1, 0, t + 2);
            MID0();
            DOMM(a1_, b0_, 1, 0);
            // P4: Q(1,1) [a1_,b1_]  vmcnt(4)   issue a0_,b0_ (t+1)  stage B1(t+2)->buf0
            STAGE(0, 1, 1, t + 2);
            VMW4();
            MID0();
            LDA(a0_, 1, 0);
            LDB(b0_, 1, 0);
            DOMM(a1_, b1_, 1, 1);
            // P5: t+1.Q(0,0) [a0_,b0_]         issue b1_(t+1)       stage A0(t+2)->buf0
            STAGE(0, 0, 0, t + 2);
            MID0();
            LDB(b1_, 1, 1);
            DOMM(a0_, b0_, 0, 0);
            // P6: Q(0,1) [a0_,b1_]             issue a1_ = LDA(1,1) stage A1(t+2)->buf0
            STAGE(0, 0, 1, t + 2);
            MID0();
            LDA(a1_, 1, 1);
            DOMM(a0_, b1_, 0, 1);
            // P7: Q(1,0) [a1_,b0_]             (no reads)           stage B0(t+3)->buf1
            STAGE(1, 1, 0, t + 3);
            MID0();
            DOMM(a1_, b0_, 1, 0);
            // P8: Q(1,1) [a1_,b1_]  vmcnt(4)   issue a0_,b0_ (next P1, buf0)
            STAGE(1, 1, 1, t + 3);
            VMW4();
            MID0();
            LDA(a0_, 0, 0);
            LDB(b0_, 0, 0);
            DOMM(a1_, b1_, 1, 1);
        }

        // ---- epilogue: C/D layout col=lane&15, row=(lane>>4)*4+rr ----
#pragma unroll
        for (int n = 0; n < 4; ++n) {
            int col = bcol + wc * 64 + n * 16 + l15;
#pragma unroll
            for (int m = 0; m < 8; ++m) {
                int row0 = brow + wr * 128 + m * 16 + kg * 4;
#pragma unroll
                for (int rr = 0; rr < 4; ++rr)
                    C[(size_t)(row0 + rr) * DIM + col] = acc[m][n][rr] + bv[n];
            }
        }
        if (r < 2) {
#pragma unroll
            for (int m = 0; m < 8; ++m)
#pragma unroll
                for (int n = 0; n < 4; ++n)
                    acc[m][n] = fzero;
        }
        q = qn; brow = nrow; bcol = ncol;
    }
#undef STAGE
#undef LDA
#undef LDB
#undef MMQ
#undef MID0
#undef DOMM
#undef VMW4
}

extern "C" void kernel_launch(void* const* d_in, const int* in_sizes, int n_in,
                              void* d_out, int out_size, void* d_ws, size_t ws_size,
                              hipStream_t stream) {
    const float* x    = (const float*)d_in[0];
    const float* w    = (const float*)d_in[1];
    const float* bias = (const float*)d_in[2];
    const float* mask = (const float*)d_in[3];
    float* out = (float*)d_out;

    const size_t wt_bytes = (size_t)DIM * DIM * sizeof(ushort);
    const size_t xb_off   = (wt_bytes + 255) & ~(size_t)255;

    ushort* wt = (ushort*)d_ws;
    ushort* xb = (ushort*)((char*)d_ws + xb_off);

    prep_kernel<<<NWT + NCVT, 256, 0, stream>>>(w, mask, x, wt, xb);
    gemm8p<<<256, 512, 0, stream>>>(xb, wt, bias, out);
}

// Round 10
// 339.671 us; speedup vs baseline: 1.7621x; 1.7621x over previous
//
#include <hip/hip_runtime.h>
#include <hip/hip_bf16.h>
#include <stdint.h>

#define DIM   3072
#define BATCH 16384

typedef __attribute__((ext_vector_type(8))) short bf16x8;
typedef __attribute__((ext_vector_type(4))) float f32x4;

__device__ __forceinline__ unsigned short f2b(float f) {
    union { float f; unsigned u; } c; c.f = f;
    unsigned u = c.u;
    unsigned r = (u + 0x7fffu + ((u >> 16) & 1u)) >> 16;
    return (unsigned short)r;
}

// ======== merged pre-pass (R6-proven) ========
// blocks [0, 2304):           wt[u][d] = bf16(mask[u][d] * w[d][u])  (48x48 tiles)
// blocks [2304, 2304+NCVT):   xb = bf16(x), grid-strided float4
#define NWT   2304
#define NCVT  2048
__global__ __launch_bounds__(256) void prep_kernel(const float* __restrict__ w,
                                                   const float* __restrict__ mask,
                                                   const float* __restrict__ x,
                                                   ushort* __restrict__ wt,
                                                   ushort* __restrict__ xb) {
    if (blockIdx.x < NWT) {
        __shared__ float tile[64][65];
        const int u0 = (blockIdx.x % 48) * 64;
        const int d0 = (blockIdx.x / 48) * 64;
        const int t  = threadIdx.x;
        const int rr = t >> 4, cc = t & 15;
#pragma unroll
        for (int it = 0; it < 4; ++it) {
            int drow = it * 16 + rr;
            float4 v = *reinterpret_cast<const float4*>(&w[(size_t)(d0 + drow) * DIM + u0 + cc * 4]);
            tile[drow][cc * 4 + 0] = v.x;
            tile[drow][cc * 4 + 1] = v.y;
            tile[drow][cc * 4 + 2] = v.z;
            tile[drow][cc * 4 + 3] = v.w;
        }
        __syncthreads();
#pragma unroll
        for (int it = 0; it < 4; ++it) {
            int urow = it * 16 + rr;
            float4 mv = *reinterpret_cast<const float4*>(&mask[(size_t)(u0 + urow) * DIM + d0 + cc * 4]);
            ushort4 o;
            o.x = f2b(tile[cc * 4 + 0][urow] * mv.x);
            o.y = f2b(tile[cc * 4 + 1][urow] * mv.y);
            o.z = f2b(tile[cc * 4 + 2][urow] * mv.z);
            o.w = f2b(tile[cc * 4 + 3][urow] * mv.w);
            *reinterpret_cast<ushort4*>(&wt[(size_t)(u0 + urow) * DIM + d0 + cc * 4]) = o;
        }
    } else {
        const int n4 = BATCH * DIM / 4;
        const int stride = NCVT * 256;
        for (int i = (blockIdx.x - NWT) * 256 + threadIdx.x; i < n4; i += stride) {
            float4 v = reinterpret_cast<const float4*>(x)[i];
            ushort4 o;
            o.x = f2b(v.x); o.y = f2b(v.y); o.z = f2b(v.z); o.w = f2b(v.w);
            reinterpret_cast<ushort4*>(xb)[i] = o;
        }
    }
}

#define GLOAD_LDS16(g, l)                                                                 \
    __builtin_amdgcn_global_load_lds((const __attribute__((address_space(1))) void*)(g),  \
                                     (__attribute__((address_space(3))) void*)(l), 16, 0, 0)

// ======================= persistent 256² 8-phase bf16 GEMM (R8-proven) =======================
// Inner 8-phase K-loop identical to R6. Each block processes 3 output tiles
// seamlessly: the K-loop's t+2/t+3 stages past t=47 target the NEXT tile's
// first panels (same buf parity as the prologue), so the pipeline never drains
// between tiles. Epilogue stores overlap the next tile's first phases.
__global__ __launch_bounds__(512, 1) void gemm8p(const ushort* __restrict__ A,
                                                 const ushort* __restrict__ B,
                                                 const float* __restrict__ bias,
                                                 float* __restrict__ C) {
    __shared__ ushort sh[2 * 2 * 16384];   // [buf][side A=0/B=1][256][64] : 128 KB

    const int tid  = threadIdx.x;
    const int lane = tid & 63;
    const int wid  = tid >> 6;   // 0..7
    const int wr   = wid >> 2;   // 0..1  (M)
    const int wc   = wid & 3;    // 0..3  (N)
    const int l15  = lane & 15;
    const int kg   = lane >> 4;
    const int sx   = lane & 7;   // swizzle XOR key on ds_read (row&7 == lane&7)

    const int srow = lane >> 3;            // 0..7
    const int sg   = (lane & 7) ^ srow;    // pre-swizzled source granule

    // persistent mapping: block bx on xcd = bx&7; 3 tiles, 32 per xcd per round
    const int bx  = blockIdx.x;
    const int xcd = bx & 7, loc = bx >> 3;
    int q    = xcd * 96 + loc;                 // round 0 tile id (bijective over rounds)
    int brow = (q / 12) * 256, bcol = (q % 12) * 256;
    int nrow = brow, ncol = bcol, nvalid = 0;  // next-tile coords, set per round

    f32x4 acc[8][4] = {};
    bf16x8 a_[8], b0_[4], b1_[4];
    const f32x4 fzero = {};

    // stage half-tile h of virtual K-tile tt into buf b, side (0=A,1=B).
    // tt >= 48 -> next tile's (tt-48); if no next tile, clamp to current t=47.
#define STAGE(b, side, h, tt)                                                              \
    do {                                                                                   \
        int _tt = (tt);                                                                    \
        int _t  = (_tt < 48) ? _tt : (nvalid ? _tt - 48 : 47);                             \
        int _rb = (_tt < 48) ? ((side) ? bcol : brow) : ((side) ? ncol : nrow);            \
        const ushort* _base = (side) ? B : A;                                              \
        int _r0 = _rb + (h) * 128 + wid * 16 + srow;                                       \
        const ushort* _g0 = _base + (size_t)_r0 * DIM + _t * 64 + sg * 8;                  \
        ushort* _l0 = sh + ((b) * 2 + (side)) * 16384 + (h) * 8192 + wid * 1024;           \
        GLOAD_LDS16(_g0, _l0);                                                             \
        GLOAD_LDS16(_g0 + (size_t)8 * DIM, _l0 + 512);                                     \
    } while (0)

#define LDA(QB, QM)                                                                        \
    _Pragma("unroll") for (int fm = 0; fm < 4; ++fm)                                       \
    _Pragma("unroll") for (int ks = 0; ks < 2; ++ks)                                       \
        a_[fm * 2 + ks] = *reinterpret_cast<const bf16x8*>(                                \
            sh + (QB) * 32768 + (wr * 128 + (QM) * 64 + fm * 16 + l15) * 64 +              \
            (((ks * 4 + kg) ^ sx) * 8));

#define LDB(DST, QB, QN)                                                                   \
    _Pragma("unroll") for (int fn = 0; fn < 2; ++fn)                                       \
    _Pragma("unroll") for (int ks = 0; ks < 2; ++ks)                                       \
        DST[fn * 2 + ks] = *reinterpret_cast<const bf16x8*>(                               \
            sh + (QB) * 32768 + 16384 + (wc * 64 + (QN) * 32 + fn * 16 + l15) * 64 +       \
            (((ks * 4 + kg) ^ sx) * 8));

#define MMQ(QM, QN, BARR)                                                                  \
    _Pragma("unroll") for (int fm = 0; fm < 4; ++fm)                                       \
    _Pragma("unroll") for (int fn = 0; fn < 2; ++fn)                                       \
    _Pragma("unroll") for (int ks = 0; ks < 2; ++ks)                                       \
        acc[(QM) * 4 + fm][(QN) * 2 + fn] = __builtin_amdgcn_mfma_f32_16x16x32_bf16(       \
            a_[fm * 2 + ks], BARR[fn * 2 + ks], acc[(QM) * 4 + fm][(QN) * 2 + fn], 0, 0, 0);

#define MIDSYNC()                                                                          \
    __builtin_amdgcn_s_barrier();                                                          \
    asm volatile("s_waitcnt lgkmcnt(0)" ::: "memory");                                     \
    __builtin_amdgcn_sched_barrier(0);                                                     \
    __builtin_amdgcn_s_setprio(1);

#define ENDPHASE()                                                                         \
    __builtin_amdgcn_s_setprio(0);                                                         \
    __builtin_amdgcn_s_barrier();

    // ---- prologue (tile 0): t0 fully -> buf0, B(t1) -> buf1; leave t1.B in flight ----
    STAGE(0, 0, 0, 0);
    STAGE(0, 0, 1, 0);
    STAGE(0, 1, 0, 0);
    STAGE(0, 1, 1, 0);
    STAGE(1, 1, 0, 1);
    STAGE(1, 1, 1, 1);
    asm volatile("s_waitcnt vmcnt(4)" ::: "memory");
    __builtin_amdgcn_s_barrier();

    for (int r = 0; r < 3; ++r) {
        nvalid = (r < 2);
        int qn = nvalid ? (xcd * 96 + (r + 1) * 32 + loc) : q;
        nrow = (qn / 12) * 256;
        ncol = (qn % 12) * 256;

        // per-tile bias preload (consumed in epilogue; drained by P4's vmcnt)
        float bv[4];
#pragma unroll
        for (int n = 0; n < 4; ++n) bv[n] = bias[bcol + wc * 64 + n * 16 + l15];

        // ---- main loop: 2 K-tiles (buf0 = t, buf1 = t+1), 8 phases (R6-identical) ----
        for (int t = 0; t < 48; t += 2) {
            // phase 1: tile t, Q(0,0)            stage A0(t+1) -> buf1
            LDA(0, 0); LDB(b0_, 0, 0);
            STAGE(1, 0, 0, t + 1);
            MIDSYNC(); MMQ(0, 0, b0_); ENDPHASE();
            // phase 2: Q(0,1)                    stage A1(t+1) -> buf1
            LDB(b1_, 0, 1);
            STAGE(1, 0, 1, t + 1);
            MIDSYNC(); MMQ(0, 1, b1_); ENDPHASE();
            // phase 3: Q(1,0)                    stage B0(t+2) -> buf0
            LDA(0, 1);
            STAGE(0, 1, 0, t + 2);
            MIDSYNC(); MMQ(1, 0, b0_); ENDPHASE();
            // phase 4: Q(1,1)                    stage B1(t+2) -> buf0, vmcnt
            STAGE(0, 1, 1, t + 2);
            asm volatile("s_waitcnt vmcnt(4)" ::: "memory");
            MIDSYNC(); MMQ(1, 1, b1_); ENDPHASE();
            // phase 5: tile t+1, Q(0,0)          stage A0(t+2) -> buf0
            LDA(1, 0); LDB(b0_, 1, 0);
            STAGE(0, 0, 0, t + 2);
            MIDSYNC(); MMQ(0, 0, b0_); ENDPHASE();
            // phase 6: Q(0,1)                    stage A1(t+2) -> buf0
            LDB(b1_, 1, 1);
            STAGE(0, 0, 1, t + 2);
            MIDSYNC(); MMQ(0, 1, b1_); ENDPHASE();
            // phase 7: Q(1,0)                    stage B0(t+3) -> buf1
            LDA(1, 1);
            STAGE(1, 1, 0, t + 3);
            MIDSYNC(); MMQ(1, 0, b0_); ENDPHASE();
            // phase 8: Q(1,1)                    stage B1(t+3) -> buf1, vmcnt
            STAGE(1, 1, 1, t + 3);
            asm volatile("s_waitcnt vmcnt(4)" ::: "memory");
            MIDSYNC(); MMQ(1, 1, b1_); ENDPHASE();
        }

        // ---- epilogue: C/D layout col=lane&15, row=(lane>>4)*4+rr ----
        // stores enter the vmcnt queue; they drain under the next tile's P1-P4.
#pragma unroll
        for (int n = 0; n < 4; ++n) {
            int col = bcol + wc * 64 + n * 16 + l15;
#pragma unroll
            for (int m = 0; m < 8; ++m) {
                int row0 = brow + wr * 128 + m * 16 + kg * 4;
#pragma unroll
                for (int rr = 0; rr < 4; ++rr)
                    C[(size_t)(row0 + rr) * DIM + col] = acc[m][n][rr] + bv[n];
            }
        }
        if (r < 2) {
#pragma unroll
            for (int m = 0; m < 8; ++m)
#pragma unroll
                for (int n = 0; n < 4; ++n)
                    acc[m][n] = fzero;
        }
        q = qn; brow = nrow; bcol = ncol;
    }
#undef STAGE
#undef LDA
#undef LDB
#undef MMQ
#undef MIDSYNC
#undef ENDPHASE
}

extern "C" void kernel_launch(void* const* d_in, const int* in_sizes, int n_in,
                              void* d_out, int out_size, void* d_ws, size_t ws_size,
                              hipStream_t stream) {
    const float* x    = (const float*)d_in[0];
    const float* w    = (const float*)d_in[1];
    const float* bias = (const float*)d_in[2];
    const float* mask = (const float*)d_in[3];
    float* out = (float*)d_out;

    const size_t wt_bytes = (size_t)DIM * DIM * sizeof(ushort);
    const size_t xb_off   = (wt_bytes + 255) & ~(size_t)255;

    ushort* wt = (ushort*)d_ws;
    ushort* xb = (ushort*)((char*)d_ws + xb_off);

    prep_kernel<<<NWT + NCVT, 256, 0, stream>>>(w, mask, x, wt, xb);
    gemm8p<<<256, 512, 0, stream>>>(xb, wt, bias, out);
}